// Round 8
// baseline (546.742 us; speedup 1.0000x reference)
//
#include <hip/hip_runtime.h>
#include <hip/hip_fp16.h>
#include <math.h>

#define BB 256
#define LL 512
#define DD 1024
#define NWQ 8         // waves per 512-thread quarter-doc block
#define QT  128       // tokens per quarter-doc block
#define NBLK (BB * 4) // 1024 quarter-doc blocks
#define VROWS 50001   // V+1 rows

// convert 8 halves packed in a float4 into 8 floats at dst[0..7]
#define CVT8(dst, v) { const __half2* hp2 = (const __half2*)&(v); float2 t; \
    t = __half22float2(hp2[0]); dst[0] = t.x; dst[1] = t.y; \
    t = __half22float2(hp2[1]); dst[2] = t.x; dst[3] = t.y; \
    t = __half22float2(hp2[2]); dst[4] = t.x; dst[5] = t.y; \
    t = __half22float2(hp2[3]); dst[6] = t.x; dst[7] = t.y; }

#define CVT8ADD(acc, off, v) { const __half2* hp2 = (const __half2*)&(v); float2 t; \
    t = __half22float2(hp2[0]); acc[(off)+0] += t.x; acc[(off)+1] += t.y; \
    t = __half22float2(hp2[1]); acc[(off)+2] += t.x; acc[(off)+3] += t.y; \
    t = __half22float2(hp2[2]); acc[(off)+4] += t.x; acc[(off)+5] += t.y; \
    t = __half22float2(hp2[3]); acc[(off)+6] += t.x; acc[(off)+7] += t.y; }

// ---------------------------------------------------------------------------
// Kernel 0: fp32 table -> fp16 table (205 MB R + 98 MB W, streaming roofline).
// ---------------------------------------------------------------------------
__global__ __launch_bounds__(256) void k_convert(const float* __restrict__ emb,
                                                 __half* __restrict__ embh) {
    const int nchunks = VROWS * (DD / 8);            // 6,400,128 chunks of 8
    const int idx = blockIdx.x * 256 + threadIdx.x;
    if (idx >= nchunks) return;
    const size_t base = (size_t)idx * 8;
    const float4 a = *(const float4*)(emb + base);
    const float4 b = *(const float4*)(emb + base + 4);
    float4 o;
    __half2* hp = (__half2*)&o;
    hp[0] = __float22half2_rn(make_float2(a.x, a.y));
    hp[1] = __float22half2_rn(make_float2(a.z, a.w));
    hp[2] = __float22half2_rn(make_float2(b.x, b.y));
    hp[3] = __float22half2_rn(make_float2(b.z, b.w));
    *(float4*)(embh + base) = o;
}

// ---------------------------------------------------------------------------
// Kernel 1: quarter-doc partial sums. 1024 blocks x 512 thr (8 waves x 16
// rows, 4-row batches). LDS ~33 KB -> 4 blocks/CU -> 32 waves/CU at the
// natural VGPR=64 tier (declared: __launch_bounds__(512, 8)). Per-CU
// outstanding loads ~= 32 waves x 8 = 256 (round-2 level, spill-free).
// ---------------------------------------------------------------------------
__global__ __launch_bounds__(512, 8)
void k_hidden_p(const int* __restrict__ tokens,
                const __half* __restrict__ embh,
                float* __restrict__ hpart) {
    __shared__ int   toks[QT];
    __shared__ float part[NWQ][DD];   // 32 KB

    const int blk  = blockIdx.x;
    const int b    = blk >> 2;
    const int qtr  = blk & 3;
    const int tid  = threadIdx.x;
    const int w    = tid >> 6;
    const int lane = tid & 63;
    const int o0   = lane * 8;
    const int o1   = 512 + lane * 8;

    if (tid < QT) toks[tid] = (tokens[b * LL + qtr * QT + tid] + 1) * DD;
    __syncthreads();

    float acc[16];
    #pragma unroll
    for (int j = 0; j < 16; ++j) acc[j] = 0.f;

    #pragma unroll 1
    for (int i = 0; i < 16; i += 4) {
        float4 v[4][2];
        #pragma unroll
        for (int r = 0; r < 4; ++r) {
            const __half* rp = embh + toks[w * 16 + i + r];
            v[r][0] = *(const float4*)(rp + o0);
            v[r][1] = *(const float4*)(rp + o1);
        }
        #pragma unroll
        for (int r = 0; r < 4; ++r) {
            CVT8ADD(acc, 0, v[r][0]);
            CVT8ADD(acc, 8, v[r][1]);
        }
    }

    *(float4*)(&part[w][o0    ]) = make_float4(acc[0],  acc[1],  acc[2],  acc[3]);
    *(float4*)(&part[w][o0 + 4]) = make_float4(acc[4],  acc[5],  acc[6],  acc[7]);
    *(float4*)(&part[w][o1    ]) = make_float4(acc[8],  acc[9],  acc[10], acc[11]);
    *(float4*)(&part[w][o1 + 4]) = make_float4(acc[12], acc[13], acc[14], acc[15]);
    __syncthreads();

    // 512 threads finalize 2 d's each
    float s0 = 0.f, s1 = 0.f;
    #pragma unroll
    for (int j = 0; j < NWQ; ++j) { s0 += part[j][tid]; s1 += part[j][tid + 512]; }
    hpart[blk * DD + tid]       = s0;
    hpart[blk * DD + tid + 512] = s1;
}

// ---------------------------------------------------------------------------
// Kernel 2: q[b,d] = sum_e W[d,e] * hidden[b,e]; hidden = (sum 4 qtrs)/L.
// grid (16, 32), 256 threads; 8 docs/block (W logical traffic 128 MB, L2-hot).
// ---------------------------------------------------------------------------
__global__ __launch_bounds__(256) void k_q(const float* __restrict__ hpart,
                                           const float* __restrict__ W,
                                           float* __restrict__ q) {
    __shared__ float hs[8][DD];   // 32 KB
    const int dt  = blockIdx.x;   // 0..15
    const int bt  = blockIdx.y;   // 0..31
    const int tid = threadIdx.x;

    #pragma unroll
    for (int j = 0; j < 8; ++j) {
        const int doc = bt * 8 + j;
        #pragma unroll
        for (int k = 0; k < 4; ++k) {
            const int d = k * 256 + tid;
            hs[j][d] = (hpart[(4 * doc + 0) * DD + d] + hpart[(4 * doc + 1) * DD + d]
                      + hpart[(4 * doc + 2) * DD + d] + hpart[(4 * doc + 3) * DD + d])
                       * (1.0f / (float)LL);
        }
    }
    __syncthreads();

    const int w = tid >> 6, lane = tid & 63;

    for (int i = 0; i < 16; ++i) {
        const int d = dt * 64 + w * 16 + i;
        float a[8];
        #pragma unroll
        for (int j = 0; j < 8; ++j) a[j] = 0.f;
        #pragma unroll
        for (int k = 0; k < 4; ++k) {
            const int off = k * 256 + lane * 4;
            const float4 wv = *(const float4*)(W + (size_t)d * DD + off);
            #pragma unroll
            for (int j = 0; j < 8; ++j) {
                const float4 h = *(const float4*)(&hs[j][off]);
                a[j] += wv.x * h.x + wv.y * h.y + wv.z * h.z + wv.w * h.w;
            }
        }
        #pragma unroll
        for (int m = 32; m; m >>= 1) {
            #pragma unroll
            for (int j = 0; j < 8; ++j) a[j] += __shfl_xor(a[j], m, 64);
        }
        if (lane == 0) {
            #pragma unroll
            for (int j = 0; j < 8; ++j) q[(bt * 8 + j) * DD + d] = a[j];
        }
    }
}

// ---------------------------------------------------------------------------
// Kernel 3: quarter-doc scores -> online softmax -> unnormalized ct partial.
// 1024 blocks x 512 thr, same gather geometry as k_hidden_p (32 waves/CU).
// Per-wave inner loop identical to the proven round-4 spill-free code.
// Writes cpart (relative to block max M) + mspart = (M, denom) per block.
// ---------------------------------------------------------------------------
__global__ __launch_bounds__(512, 8)
void k_attn_p(const int* __restrict__ tokens,
              const __half* __restrict__ embh,
              const float* __restrict__ q,
              float* __restrict__ cpart,
              float* __restrict__ mspart) {
    __shared__ int   toks[QT];
    __shared__ float ctp[NWQ][DD];   // 32 KB
    __shared__ float mw[NWQ], sw[NWQ];

    const int blk  = blockIdx.x;
    const int b    = blk >> 2;
    const int qtr  = blk & 3;
    const int tid  = threadIdx.x;
    const int w    = tid >> 6;
    const int lane = tid & 63;
    const int o0   = lane * 8;
    const int o1   = 512 + lane * 8;

    if (tid < QT) toks[tid] = (tokens[b * LL + qtr * QT + tid] + 1) * DD;
    __syncthreads();

    float qa[16];
    {
        const float4 q00 = *(const float4*)(q + b * DD + o0);
        const float4 q01 = *(const float4*)(q + b * DD + o0 + 4);
        const float4 q10 = *(const float4*)(q + b * DD + o1);
        const float4 q11 = *(const float4*)(q + b * DD + o1 + 4);
        qa[0]=q00.x; qa[1]=q00.y; qa[2]=q00.z; qa[3]=q00.w;
        qa[4]=q01.x; qa[5]=q01.y; qa[6]=q01.z; qa[7]=q01.w;
        qa[8]=q10.x; qa[9]=q10.y; qa[10]=q10.z; qa[11]=q10.w;
        qa[12]=q11.x; qa[13]=q11.y; qa[14]=q11.z; qa[15]=q11.w;
    }

    float m = -1e30f, s = 0.f;
    float ct[16];
    #pragma unroll
    for (int j = 0; j < 16; ++j) ct[j] = 0.f;

    #pragma unroll 1
    for (int i = 0; i < 16; i += 4) {
        float4 v[4][2];
        #pragma unroll
        for (int r = 0; r < 4; ++r) {
            const __half* rp = embh + toks[w * 16 + i + r];
            v[r][0] = *(const float4*)(rp + o0);
            v[r][1] = *(const float4*)(rp + o1);
        }

        float p[4];
        #pragma unroll
        for (int r = 0; r < 4; ++r) {
            float e8[8];
            float pp = 0.f;
            CVT8(e8, v[r][0]);
            #pragma unroll
            for (int j = 0; j < 8; ++j) pp += e8[j] * qa[j];
            CVT8(e8, v[r][1]);
            #pragma unroll
            for (int j = 0; j < 8; ++j) pp += e8[j] * qa[8 + j];
            p[r] = pp;
        }
        #pragma unroll
        for (int mm = 32; mm; mm >>= 1) {
            p[0] += __shfl_xor(p[0], mm, 64);
            p[1] += __shfl_xor(p[1], mm, 64);
            p[2] += __shfl_xor(p[2], mm, 64);
            p[3] += __shfl_xor(p[3], mm, 64);
        }

        const float nm = fmaxf(fmaxf(m, fmaxf(p[0], p[1])), fmaxf(p[2], p[3]));
        const float f  = __expf(m - nm);
        const float w0 = __expf(p[0] - nm);
        const float w1 = __expf(p[1] - nm);
        const float w2 = __expf(p[2] - nm);
        const float w3 = __expf(p[3] - nm);
        s = s * f + w0 + w1 + w2 + w3;

        #pragma unroll
        for (int j = 0; j < 16; ++j) ct[j] *= f;
        {
            float e8[8];
            CVT8(e8, v[0][0]); { for (int j = 0; j < 8; ++j) ct[j]   += w0 * e8[j]; }
            CVT8(e8, v[0][1]); { for (int j = 0; j < 8; ++j) ct[8+j] += w0 * e8[j]; }
            CVT8(e8, v[1][0]); { for (int j = 0; j < 8; ++j) ct[j]   += w1 * e8[j]; }
            CVT8(e8, v[1][1]); { for (int j = 0; j < 8; ++j) ct[8+j] += w1 * e8[j]; }
            CVT8(e8, v[2][0]); { for (int j = 0; j < 8; ++j) ct[j]   += w2 * e8[j]; }
            CVT8(e8, v[2][1]); { for (int j = 0; j < 8; ++j) ct[8+j] += w2 * e8[j]; }
            CVT8(e8, v[3][0]); { for (int j = 0; j < 8; ++j) ct[j]   += w3 * e8[j]; }
            CVT8(e8, v[3][1]); { for (int j = 0; j < 8; ++j) ct[8+j] += w3 * e8[j]; }
        }
        m = nm;
    }

    *(float4*)(&ctp[w][o0    ]) = make_float4(ct[0],  ct[1],  ct[2],  ct[3]);
    *(float4*)(&ctp[w][o0 + 4]) = make_float4(ct[4],  ct[5],  ct[6],  ct[7]);
    *(float4*)(&ctp[w][o1    ]) = make_float4(ct[8],  ct[9],  ct[10], ct[11]);
    *(float4*)(&ctp[w][o1 + 4]) = make_float4(ct[12], ct[13], ct[14], ct[15]);
    if (lane == 0) { mw[w] = m; sw[w] = s; }
    __syncthreads();

    float M = -1e30f;
    #pragma unroll
    for (int j = 0; j < NWQ; ++j) M = fmaxf(M, mw[j]);
    float denom = 0.f, sc[NWQ];
    #pragma unroll
    for (int j = 0; j < NWQ; ++j) { sc[j] = __expf(mw[j] - M); denom += sc[j] * sw[j]; }

    float a0 = 0.f, a1 = 0.f;
    #pragma unroll
    for (int j = 0; j < NWQ; ++j) { a0 += sc[j] * ctp[j][tid]; a1 += sc[j] * ctp[j][tid + 512]; }
    cpart[blk * DD + tid]       = a0;            // unnormalized, relative to M
    cpart[blk * DD + tid + 512] = a1;
    if (tid == 0) { mspart[blk * 2] = M; mspart[blk * 2 + 1] = denom; }
}

// ---------------------------------------------------------------------------
// Kernel 4: merge the four quarter-doc partials (4 MB R + 1 MB W, ~2 us).
// ---------------------------------------------------------------------------
__global__ __launch_bounds__(1024) void k_merge(const float* __restrict__ cpart,
                                                const float* __restrict__ mspart,
                                                float* __restrict__ out) {
    const int b   = blockIdx.x;
    const int tid = threadIdx.x;
    float Mk[4], Sk[4];
    #pragma unroll
    for (int k = 0; k < 4; ++k) {
        Mk[k] = mspart[(4 * b + k) * 2];
        Sk[k] = mspart[(4 * b + k) * 2 + 1];
    }
    float M = fmaxf(fmaxf(Mk[0], Mk[1]), fmaxf(Mk[2], Mk[3]));
    float f[4], denom = 0.f;
    #pragma unroll
    for (int k = 0; k < 4; ++k) { f[k] = __expf(Mk[k] - M); denom += f[k] * Sk[k]; }
    const float inv = 1.0f / denom;
    float a = 0.f;
    #pragma unroll
    for (int k = 0; k < 4; ++k) a += f[k] * cpart[(4 * b + k) * DD + tid];
    out[b * DD + tid] = a * inv;
}

// ---------------------------------------------------------------------------
extern "C" void kernel_launch(void* const* d_in, const int* in_sizes, int n_in,
                              void* d_out, int out_size, void* d_ws, size_t ws_size,
                              hipStream_t stream) {
    const int*   tokens = (const int*)d_in[0];
    // d_in[1] = max_len (scalar), fixed to LL
    const float* emb    = (const float*)d_in[2];
    const float* W      = (const float*)d_in[3];
    float*       out    = (float*)d_out;

    float*  hpart  = (float*)d_ws;                   // 1024*1024 f = 4 MB
    float*  q      = hpart  + NBLK * DD;             // 1 MB
    float*  cpart  = q      + BB * DD;               // 4 MB
    float*  mspart = cpart  + NBLK * DD;             // 8 KB
    __half* embh   = (__half*)(mspart + 2 * NBLK);   // ~98 MB (16B-aligned)

    const int nchunks = VROWS * (DD / 8);
    k_convert<<<(nchunks + 255) / 256, 256, 0, stream>>>(emb, embh);
    k_hidden_p<<<NBLK, 512, 0, stream>>>(tokens, embh, hpart);
    dim3 g2(DD / 64, BB / 8);
    k_q<<<g2, 256, 0, stream>>>(hpart, W, q);
    k_attn_p<<<NBLK, 512, 0, stream>>>(tokens, embh, q, cpart, mspart);
    k_merge<<<BB, 1024, 0, stream>>>(cpart, mspart, out);
}

// Round 9
// 401.775 us; speedup vs baseline: 1.3608x; 1.3608x over previous
//
#include <hip/hip_runtime.h>
#include <hip/hip_fp16.h>
#include <math.h>

#define BB 256
#define LL 512
#define DD 1024
#define NWQ 8         // waves per 512-thread quarter-doc block
#define QT  128       // tokens per quarter-doc block
#define NBLK (BB * 4) // 1024 quarter-doc blocks
#define VROWS 50001   // V+1 rows

// convert 8 halves packed in a float4 into 8 floats at dst[0..7]
#define CVT8(dst, v) { const __half2* hp2 = (const __half2*)&(v); float2 t; \
    t = __half22float2(hp2[0]); dst[0] = t.x; dst[1] = t.y; \
    t = __half22float2(hp2[1]); dst[2] = t.x; dst[3] = t.y; \
    t = __half22float2(hp2[2]); dst[4] = t.x; dst[5] = t.y; \
    t = __half22float2(hp2[3]); dst[6] = t.x; dst[7] = t.y; }

#define CVT8ADD(acc, off, v) { const __half2* hp2 = (const __half2*)&(v); float2 t; \
    t = __half22float2(hp2[0]); acc[(off)+0] += t.x; acc[(off)+1] += t.y; \
    t = __half22float2(hp2[1]); acc[(off)+2] += t.x; acc[(off)+3] += t.y; \
    t = __half22float2(hp2[2]); acc[(off)+4] += t.x; acc[(off)+5] += t.y; \
    t = __half22float2(hp2[3]); acc[(off)+6] += t.x; acc[(off)+7] += t.y; }

// ---------------------------------------------------------------------------
// Kernel 0: fp32 table -> fp16 table (205 MB R + 98 MB W, streaming roofline).
// ---------------------------------------------------------------------------
__global__ __launch_bounds__(256) void k_convert(const float* __restrict__ emb,
                                                 __half* __restrict__ embh) {
    const int nchunks = VROWS * (DD / 8);            // 6,400,128 chunks of 8
    const int idx = blockIdx.x * 256 + threadIdx.x;
    if (idx >= nchunks) return;
    const size_t base = (size_t)idx * 8;
    const float4 a = *(const float4*)(emb + base);
    const float4 b = *(const float4*)(emb + base + 4);
    float4 o;
    __half2* hp = (__half2*)&o;
    hp[0] = __float22half2_rn(make_float2(a.x, a.y));
    hp[1] = __float22half2_rn(make_float2(a.z, a.w));
    hp[2] = __float22half2_rn(make_float2(b.x, b.y));
    hp[3] = __float22half2_rn(make_float2(b.z, b.w));
    *(float4*)(embh + base) = o;
}

// ---------------------------------------------------------------------------
// Kernel 1: quarter-doc partial sums. 1024 blocks x 512 thr (8 waves x 16
// rows, 4-row batches = 8 x 1KB loads in flight/wave). LDS ~33 KB -> 4
// blocks/CU -> 32 waves/CU if VGPR <= 64.
// __launch_bounds__(512, 4): cap 128 -> allocator's observed half-tier
// heuristic (r4: cap128->64, r8: cap64->32) should land on 64. Batch
// liveness ~55 regs -> spill-free at 64.
// ---------------------------------------------------------------------------
__global__ __launch_bounds__(512, 4)
void k_hidden_p(const int* __restrict__ tokens,
                const __half* __restrict__ embh,
                float* __restrict__ hpart) {
    __shared__ int   toks[QT];
    __shared__ float part[NWQ][DD];   // 32 KB

    const int blk  = blockIdx.x;
    const int b    = blk >> 2;
    const int qtr  = blk & 3;
    const int tid  = threadIdx.x;
    const int w    = tid >> 6;
    const int lane = tid & 63;
    const int o0   = lane * 8;
    const int o1   = 512 + lane * 8;

    if (tid < QT) toks[tid] = (tokens[b * LL + qtr * QT + tid] + 1) * DD;
    __syncthreads();

    float acc[16];
    #pragma unroll
    for (int j = 0; j < 16; ++j) acc[j] = 0.f;

    #pragma unroll 1
    for (int i = 0; i < 16; i += 4) {
        float4 v[4][2];
        #pragma unroll
        for (int r = 0; r < 4; ++r) {
            const __half* rp = embh + toks[w * 16 + i + r];
            v[r][0] = *(const float4*)(rp + o0);
            v[r][1] = *(const float4*)(rp + o1);
        }
        #pragma unroll
        for (int r = 0; r < 4; ++r) {
            CVT8ADD(acc, 0, v[r][0]);
            CVT8ADD(acc, 8, v[r][1]);
        }
    }

    *(float4*)(&part[w][o0    ]) = make_float4(acc[0],  acc[1],  acc[2],  acc[3]);
    *(float4*)(&part[w][o0 + 4]) = make_float4(acc[4],  acc[5],  acc[6],  acc[7]);
    *(float4*)(&part[w][o1    ]) = make_float4(acc[8],  acc[9],  acc[10], acc[11]);
    *(float4*)(&part[w][o1 + 4]) = make_float4(acc[12], acc[13], acc[14], acc[15]);
    __syncthreads();

    // 512 threads finalize 2 d's each
    float s0 = 0.f, s1 = 0.f;
    #pragma unroll
    for (int j = 0; j < NWQ; ++j) { s0 += part[j][tid]; s1 += part[j][tid + 512]; }
    hpart[blk * DD + tid]       = s0;
    hpart[blk * DD + tid + 512] = s1;
}

// ---------------------------------------------------------------------------
// Kernel 2: q[b,d] = sum_e W[d,e] * hidden[b,e]; hidden = (sum 4 qtrs)/L.
// grid (16, 32), 256 threads; 8 docs/block (W logical traffic 128 MB, L2-hot).
// ---------------------------------------------------------------------------
__global__ __launch_bounds__(256) void k_q(const float* __restrict__ hpart,
                                           const float* __restrict__ W,
                                           float* __restrict__ q) {
    __shared__ float hs[8][DD];   // 32 KB
    const int dt  = blockIdx.x;   // 0..15
    const int bt  = blockIdx.y;   // 0..31
    const int tid = threadIdx.x;

    #pragma unroll
    for (int j = 0; j < 8; ++j) {
        const int doc = bt * 8 + j;
        #pragma unroll
        for (int k = 0; k < 4; ++k) {
            const int d = k * 256 + tid;
            hs[j][d] = (hpart[(4 * doc + 0) * DD + d] + hpart[(4 * doc + 1) * DD + d]
                      + hpart[(4 * doc + 2) * DD + d] + hpart[(4 * doc + 3) * DD + d])
                       * (1.0f / (float)LL);
        }
    }
    __syncthreads();

    const int w = tid >> 6, lane = tid & 63;

    for (int i = 0; i < 16; ++i) {
        const int d = dt * 64 + w * 16 + i;
        float a[8];
        #pragma unroll
        for (int j = 0; j < 8; ++j) a[j] = 0.f;
        #pragma unroll
        for (int k = 0; k < 4; ++k) {
            const int off = k * 256 + lane * 4;
            const float4 wv = *(const float4*)(W + (size_t)d * DD + off);
            #pragma unroll
            for (int j = 0; j < 8; ++j) {
                const float4 h = *(const float4*)(&hs[j][off]);
                a[j] += wv.x * h.x + wv.y * h.y + wv.z * h.z + wv.w * h.w;
            }
        }
        #pragma unroll
        for (int m = 32; m; m >>= 1) {
            #pragma unroll
            for (int j = 0; j < 8; ++j) a[j] += __shfl_xor(a[j], m, 64);
        }
        if (lane == 0) {
            #pragma unroll
            for (int j = 0; j < 8; ++j) q[(bt * 8 + j) * DD + d] = a[j];
        }
    }
}

// ---------------------------------------------------------------------------
// Kernel 3: quarter-doc scores -> online softmax -> unnormalized ct partial.
// 1024 blocks x 512 thr, 32 waves/CU target. TWO-row batches: worst-case
// liveness v[2][2](16) + qa(16) + ct(16) + temps ~58 regs -> provably fits
// the 64-reg tier (4-row was marginal and spilled whenever the allocator
// shrank). 4 x 1KB loads in flight/wave x 32 waves = 128 KB/CU.
// ---------------------------------------------------------------------------
__global__ __launch_bounds__(512, 4)
void k_attn_p(const int* __restrict__ tokens,
              const __half* __restrict__ embh,
              const float* __restrict__ q,
              float* __restrict__ cpart,
              float* __restrict__ mspart) {
    __shared__ int   toks[QT];
    __shared__ float ctp[NWQ][DD];   // 32 KB
    __shared__ float mw[NWQ], sw[NWQ];

    const int blk  = blockIdx.x;
    const int b    = blk >> 2;
    const int qtr  = blk & 3;
    const int tid  = threadIdx.x;
    const int w    = tid >> 6;
    const int lane = tid & 63;
    const int o0   = lane * 8;
    const int o1   = 512 + lane * 8;

    if (tid < QT) toks[tid] = (tokens[b * LL + qtr * QT + tid] + 1) * DD;
    __syncthreads();

    float qa[16];
    {
        const float4 q00 = *(const float4*)(q + b * DD + o0);
        const float4 q01 = *(const float4*)(q + b * DD + o0 + 4);
        const float4 q10 = *(const float4*)(q + b * DD + o1);
        const float4 q11 = *(const float4*)(q + b * DD + o1 + 4);
        qa[0]=q00.x; qa[1]=q00.y; qa[2]=q00.z; qa[3]=q00.w;
        qa[4]=q01.x; qa[5]=q01.y; qa[6]=q01.z; qa[7]=q01.w;
        qa[8]=q10.x; qa[9]=q10.y; qa[10]=q10.z; qa[11]=q10.w;
        qa[12]=q11.x; qa[13]=q11.y; qa[14]=q11.z; qa[15]=q11.w;
    }

    float m = -1e30f, s = 0.f;
    float ct[16];
    #pragma unroll
    for (int j = 0; j < 16; ++j) ct[j] = 0.f;

    #pragma unroll 1
    for (int i = 0; i < 16; i += 2) {
        float4 v[2][2];
        #pragma unroll
        for (int r = 0; r < 2; ++r) {
            const __half* rp = embh + toks[w * 16 + i + r];
            v[r][0] = *(const float4*)(rp + o0);
            v[r][1] = *(const float4*)(rp + o1);
        }

        float p0, p1;
        {
            float e8[8];
            float pp = 0.f;
            CVT8(e8, v[0][0]);
            #pragma unroll
            for (int j = 0; j < 8; ++j) pp += e8[j] * qa[j];
            CVT8(e8, v[0][1]);
            #pragma unroll
            for (int j = 0; j < 8; ++j) pp += e8[j] * qa[8 + j];
            p0 = pp;
            pp = 0.f;
            CVT8(e8, v[1][0]);
            #pragma unroll
            for (int j = 0; j < 8; ++j) pp += e8[j] * qa[j];
            CVT8(e8, v[1][1]);
            #pragma unroll
            for (int j = 0; j < 8; ++j) pp += e8[j] * qa[8 + j];
            p1 = pp;
        }
        #pragma unroll
        for (int mm = 32; mm; mm >>= 1) {
            p0 += __shfl_xor(p0, mm, 64);
            p1 += __shfl_xor(p1, mm, 64);
        }

        const float nm = fmaxf(m, fmaxf(p0, p1));
        const float f  = __expf(m - nm);
        const float w0 = __expf(p0 - nm);
        const float w1 = __expf(p1 - nm);
        s = s * f + w0 + w1;

        #pragma unroll
        for (int j = 0; j < 16; ++j) ct[j] *= f;
        {
            float e8[8];
            CVT8(e8, v[0][0]);
            #pragma unroll
            for (int j = 0; j < 8; ++j) ct[j]     += w0 * e8[j];
            CVT8(e8, v[0][1]);
            #pragma unroll
            for (int j = 0; j < 8; ++j) ct[8 + j] += w0 * e8[j];
            CVT8(e8, v[1][0]);
            #pragma unroll
            for (int j = 0; j < 8; ++j) ct[j]     += w1 * e8[j];
            CVT8(e8, v[1][1]);
            #pragma unroll
            for (int j = 0; j < 8; ++j) ct[8 + j] += w1 * e8[j];
        }
        m = nm;
    }

    *(float4*)(&ctp[w][o0    ]) = make_float4(ct[0],  ct[1],  ct[2],  ct[3]);
    *(float4*)(&ctp[w][o0 + 4]) = make_float4(ct[4],  ct[5],  ct[6],  ct[7]);
    *(float4*)(&ctp[w][o1    ]) = make_float4(ct[8],  ct[9],  ct[10], ct[11]);
    *(float4*)(&ctp[w][o1 + 4]) = make_float4(ct[12], ct[13], ct[14], ct[15]);
    if (lane == 0) { mw[w] = m; sw[w] = s; }
    __syncthreads();

    float M = -1e30f;
    #pragma unroll
    for (int j = 0; j < NWQ; ++j) M = fmaxf(M, mw[j]);
    float denom = 0.f, sc[NWQ];
    #pragma unroll
    for (int j = 0; j < NWQ; ++j) { sc[j] = __expf(mw[j] - M); denom += sc[j] * sw[j]; }

    float a0 = 0.f, a1 = 0.f;
    #pragma unroll
    for (int j = 0; j < NWQ; ++j) { a0 += sc[j] * ctp[j][tid]; a1 += sc[j] * ctp[j][tid + 512]; }
    cpart[blk * DD + tid]       = a0;            // unnormalized, relative to M
    cpart[blk * DD + tid + 512] = a1;
    if (tid == 0) { mspart[blk * 2] = M; mspart[blk * 2 + 1] = denom; }
}

// ---------------------------------------------------------------------------
// Kernel 4: merge the four quarter-doc partials (4 MB R + 1 MB W, ~2 us).
// ---------------------------------------------------------------------------
__global__ __launch_bounds__(1024) void k_merge(const float* __restrict__ cpart,
                                                const float* __restrict__ mspart,
                                                float* __restrict__ out) {
    const int b   = blockIdx.x;
    const int tid = threadIdx.x;
    float Mk[4], Sk[4];
    #pragma unroll
    for (int k = 0; k < 4; ++k) {
        Mk[k] = mspart[(4 * b + k) * 2];
        Sk[k] = mspart[(4 * b + k) * 2 + 1];
    }
    float M = fmaxf(fmaxf(Mk[0], Mk[1]), fmaxf(Mk[2], Mk[3]));
    float f[4], denom = 0.f;
    #pragma unroll
    for (int k = 0; k < 4; ++k) { f[k] = __expf(Mk[k] - M); denom += f[k] * Sk[k]; }
    const float inv = 1.0f / denom;
    float a = 0.f;
    #pragma unroll
    for (int k = 0; k < 4; ++k) a += f[k] * cpart[(4 * b + k) * DD + tid];
    out[b * DD + tid] = a * inv;
}

// ---------------------------------------------------------------------------
extern "C" void kernel_launch(void* const* d_in, const int* in_sizes, int n_in,
                              void* d_out, int out_size, void* d_ws, size_t ws_size,
                              hipStream_t stream) {
    const int*   tokens = (const int*)d_in[0];
    // d_in[1] = max_len (scalar), fixed to LL
    const float* emb    = (const float*)d_in[2];
    const float* W      = (const float*)d_in[3];
    float*       out    = (float*)d_out;

    float*  hpart  = (float*)d_ws;                   // 1024*1024 f = 4 MB
    float*  q      = hpart  + NBLK * DD;             // 1 MB
    float*  cpart  = q      + BB * DD;               // 4 MB
    float*  mspart = cpart  + NBLK * DD;             // 8 KB
    __half* embh   = (__half*)(mspart + 2 * NBLK);   // ~98 MB (16B-aligned)

    const int nchunks = VROWS * (DD / 8);
    k_convert<<<(nchunks + 255) / 256, 256, 0, stream>>>(emb, embh);
    k_hidden_p<<<NBLK, 512, 0, stream>>>(tokens, embh, hpart);
    dim3 g2(DD / 64, BB / 8);
    k_q<<<g2, 256, 0, stream>>>(hpart, W, q);
    k_attn_p<<<NBLK, 512, 0, stream>>>(tokens, embh, q, cpart, mspart);
    k_merge<<<BB, 1024, 0, stream>>>(cpart, mspart, out);
}

// Round 10
// 391.137 us; speedup vs baseline: 1.3978x; 1.0272x over previous
//
#include <hip/hip_runtime.h>
#include <hip/hip_fp16.h>
#include <math.h>

#define BB 256
#define LL 512
#define DD 1024
#define NW 16         // waves per 1024-thread block
#define VROWS 50001   // V+1 rows

// convert 8 halves packed in a float4 into 8 floats at dst[off..off+7]
#define CVT8(dst, off, v) { const __half2* hp2 = (const __half2*)&(v); float2 t; \
    t = __half22float2(hp2[0]); dst[(off)+0] = t.x; dst[(off)+1] = t.y; \
    t = __half22float2(hp2[1]); dst[(off)+2] = t.x; dst[(off)+3] = t.y; \
    t = __half22float2(hp2[2]); dst[(off)+4] = t.x; dst[(off)+5] = t.y; \
    t = __half22float2(hp2[3]); dst[(off)+6] = t.x; dst[(off)+7] = t.y; }

#define CVT8ADD(acc, off, v) { const __half2* hp2 = (const __half2*)&(v); float2 t; \
    t = __half22float2(hp2[0]); acc[(off)+0] += t.x; acc[(off)+1] += t.y; \
    t = __half22float2(hp2[1]); acc[(off)+2] += t.x; acc[(off)+3] += t.y; \
    t = __half22float2(hp2[2]); acc[(off)+4] += t.x; acc[(off)+5] += t.y; \
    t = __half22float2(hp2[3]); acc[(off)+6] += t.x; acc[(off)+7] += t.y; }

// ---------------------------------------------------------------------------
// Kernel 0: fp32 table -> fp16 table (one-time per call, 205 MB R + 98 MB W).
// ---------------------------------------------------------------------------
__global__ __launch_bounds__(256) void k_convert(const float* __restrict__ emb,
                                                 __half* __restrict__ embh) {
    const int nchunks = VROWS * (DD / 8);            // 6,400,128 chunks of 8
    const int idx = blockIdx.x * 256 + threadIdx.x;
    if (idx >= nchunks) return;
    const size_t base = (size_t)idx * 8;
    const float4 a = *(const float4*)(emb + base);
    const float4 b = *(const float4*)(emb + base + 4);
    float4 o;
    __half2* hp = (__half2*)&o;
    hp[0] = __float22half2_rn(make_float2(a.x, a.y));
    hp[1] = __float22half2_rn(make_float2(a.z, a.w));
    hp[2] = __float22half2_rn(make_float2(b.x, b.y));
    hp[3] = __float22half2_rn(make_float2(b.z, b.w));
    *(float4*)(embh + base) = o;
}

// ---------------------------------------------------------------------------
// Kernel 1: hidden[b,:] = (1/L) * sum_l embh[tok+1, :]  (fp16 rows, fp32 acc)
// Grid 256, 16 waves; wave sums 32 rows in 4-row batches (8x16B in flight).
// Lane owns 16 d's: [lane*8, lane*8+8) and [512+lane*8, ...+8).
// __launch_bounds__(1024,4): VGPR cap 128 -> no spill (round-3 lesson).
// ---------------------------------------------------------------------------
__global__ __launch_bounds__(1024, 4) void k_hidden(const int* __restrict__ tokens,
                                                    const __half* __restrict__ embh,
                                                    float* __restrict__ hidden) {
    __shared__ int   toks[LL];
    __shared__ float part[NW][DD];   // 64 KB

    const int b    = blockIdx.x;
    const int tid  = threadIdx.x;
    const int w    = tid >> 6;
    const int lane = tid & 63;
    const int o0   = lane * 8;
    const int o1   = 512 + lane * 8;

    if (tid < LL) toks[tid] = (tokens[b * LL + tid] + 1) * DD;
    __syncthreads();

    float acc[16];
    #pragma unroll
    for (int j = 0; j < 16; ++j) acc[j] = 0.f;

    for (int i = 0; i < 32; i += 4) {
        const __half* r0 = embh + toks[w * 32 + i + 0];
        const __half* r1 = embh + toks[w * 32 + i + 1];
        const __half* r2 = embh + toks[w * 32 + i + 2];
        const __half* r3 = embh + toks[w * 32 + i + 3];
        const float4 a00 = *(const float4*)(r0 + o0);
        const float4 a01 = *(const float4*)(r0 + o1);
        const float4 a10 = *(const float4*)(r1 + o0);
        const float4 a11 = *(const float4*)(r1 + o1);
        const float4 a20 = *(const float4*)(r2 + o0);
        const float4 a21 = *(const float4*)(r2 + o1);
        const float4 a30 = *(const float4*)(r3 + o0);
        const float4 a31 = *(const float4*)(r3 + o1);
        CVT8ADD(acc, 0, a00); CVT8ADD(acc, 8, a01);
        CVT8ADD(acc, 0, a10); CVT8ADD(acc, 8, a11);
        CVT8ADD(acc, 0, a20); CVT8ADD(acc, 8, a21);
        CVT8ADD(acc, 0, a30); CVT8ADD(acc, 8, a31);
    }

    *(float4*)(&part[w][o0    ]) = make_float4(acc[0],  acc[1],  acc[2],  acc[3]);
    *(float4*)(&part[w][o0 + 4]) = make_float4(acc[4],  acc[5],  acc[6],  acc[7]);
    *(float4*)(&part[w][o1    ]) = make_float4(acc[8],  acc[9],  acc[10], acc[11]);
    *(float4*)(&part[w][o1 + 4]) = make_float4(acc[12], acc[13], acc[14], acc[15]);
    __syncthreads();

    float s = 0.f;
    #pragma unroll
    for (int j = 0; j < NW; ++j) s += part[j][tid];
    hidden[b * DD + tid] = s * (1.0f / (float)LL);
}

// ---------------------------------------------------------------------------
// Kernel 2: q[b,d] = sum_e W[d,e] * hidden[b,e]   (fp32, proven round-0 form)
// grid (16, 64), 256 threads; 4 docs/block amortize W reads (L2-hot).
// ---------------------------------------------------------------------------
__global__ __launch_bounds__(256) void k_q(const float* __restrict__ hidden,
                                           const float* __restrict__ W,
                                           float* __restrict__ q) {
    __shared__ float hs[4][DD];
    const int dt  = blockIdx.x;
    const int bt  = blockIdx.y;
    const int tid = threadIdx.x;

    #pragma unroll
    for (int j = 0; j < 4; ++j)
        #pragma unroll
        for (int k = 0; k < 4; ++k)
            hs[j][k * 256 + tid] = hidden[(bt * 4 + j) * DD + k * 256 + tid];
    __syncthreads();

    const int w = tid >> 6, lane = tid & 63;

    for (int i = 0; i < 16; ++i) {
        const int d = dt * 64 + w * 16 + i;
        float a0 = 0.f, a1 = 0.f, a2 = 0.f, a3 = 0.f;
        #pragma unroll
        for (int k = 0; k < 4; ++k) {
            const int off = k * 256 + lane * 4;
            const float4 wv = *(const float4*)(W + (size_t)d * DD + off);
            const float4 h0 = *(const float4*)(&hs[0][off]);
            const float4 h1 = *(const float4*)(&hs[1][off]);
            const float4 h2 = *(const float4*)(&hs[2][off]);
            const float4 h3 = *(const float4*)(&hs[3][off]);
            a0 += wv.x * h0.x + wv.y * h0.y + wv.z * h0.z + wv.w * h0.w;
            a1 += wv.x * h1.x + wv.y * h1.y + wv.z * h1.z + wv.w * h1.w;
            a2 += wv.x * h2.x + wv.y * h2.y + wv.z * h2.z + wv.w * h2.w;
            a3 += wv.x * h3.x + wv.y * h3.y + wv.z * h3.z + wv.w * h3.w;
        }
        #pragma unroll
        for (int m = 32; m; m >>= 1) {
            a0 += __shfl_xor(a0, m, 64);
            a1 += __shfl_xor(a1, m, 64);
            a2 += __shfl_xor(a2, m, 64);
            a3 += __shfl_xor(a3, m, 64);
        }
        if (lane == 0) {
            q[(bt * 4 + 0) * DD + d] = a0;
            q[(bt * 4 + 1) * DD + d] = a1;
            q[(bt * 4 + 2) * DD + d] = a2;
            q[(bt * 4 + 3) * DD + d] = a3;
        }
    }
}

// ---------------------------------------------------------------------------
// Kernel 3: scores -> online softmax -> ct, fp16 rows / fp32 math.
// Grid 256, 16 waves x 32 rows, 2-row batch (one rescale per pair).
// VGPR budget ~90 under the 128 cap from __launch_bounds__(1024,4).
// ---------------------------------------------------------------------------
__global__ __launch_bounds__(1024, 4) void k_attn(const int* __restrict__ tokens,
                                                  const __half* __restrict__ embh,
                                                  const float* __restrict__ q,
                                                  float* __restrict__ out) {
    __shared__ int   toks[LL];
    __shared__ float ctp[NW][DD];   // 64 KB
    __shared__ float mw[NW], sw[NW];

    const int b    = blockIdx.x;
    const int tid  = threadIdx.x;
    const int w    = tid >> 6;
    const int lane = tid & 63;
    const int o0   = lane * 8;
    const int o1   = 512 + lane * 8;

    if (tid < LL) toks[tid] = (tokens[b * LL + tid] + 1) * DD;
    __syncthreads();

    float qa[16];
    {
        const float4 q00 = *(const float4*)(q + b * DD + o0);
        const float4 q01 = *(const float4*)(q + b * DD + o0 + 4);
        const float4 q10 = *(const float4*)(q + b * DD + o1);
        const float4 q11 = *(const float4*)(q + b * DD + o1 + 4);
        qa[0]=q00.x; qa[1]=q00.y; qa[2]=q00.z; qa[3]=q00.w;
        qa[4]=q01.x; qa[5]=q01.y; qa[6]=q01.z; qa[7]=q01.w;
        qa[8]=q10.x; qa[9]=q10.y; qa[10]=q10.z; qa[11]=q10.w;
        qa[12]=q11.x; qa[13]=q11.y; qa[14]=q11.z; qa[15]=q11.w;
    }

    float m = -1e30f, s = 0.f;
    float ct[16];
    #pragma unroll
    for (int j = 0; j < 16; ++j) ct[j] = 0.f;

    for (int i = 0; i < 32; i += 2) {
        const __half* ra = embh + toks[w * 32 + i    ];
        const __half* rb = embh + toks[w * 32 + i + 1];
        const float4 va0 = *(const float4*)(ra + o0);
        const float4 va1 = *(const float4*)(ra + o1);
        const float4 vb0 = *(const float4*)(rb + o0);
        const float4 vb1 = *(const float4*)(rb + o1);

        float ea[16], eb[16];
        CVT8(ea, 0, va0); CVT8(ea, 8, va1);
        CVT8(eb, 0, vb0); CVT8(eb, 8, vb1);

        float p0 = 0.f, p1 = 0.f;
        #pragma unroll
        for (int j = 0; j < 16; ++j) { p0 += ea[j] * qa[j]; p1 += eb[j] * qa[j]; }
        #pragma unroll
        for (int mm = 32; mm; mm >>= 1) {
            p0 += __shfl_xor(p0, mm, 64);
            p1 += __shfl_xor(p1, mm, 64);
        }

        const float nm = fmaxf(m, fmaxf(p0, p1));
        const float f  = __expf(m - nm);
        const float w0 = __expf(p0 - nm);
        const float w1 = __expf(p1 - nm);
        s = s * f + w0 + w1;
        #pragma unroll
        for (int j = 0; j < 16; ++j) ct[j] = ct[j] * f + w0 * ea[j] + w1 * eb[j];
        m = nm;
    }

    *(float4*)(&ctp[w][o0    ]) = make_float4(ct[0],  ct[1],  ct[2],  ct[3]);
    *(float4*)(&ctp[w][o0 + 4]) = make_float4(ct[4],  ct[5],  ct[6],  ct[7]);
    *(float4*)(&ctp[w][o1    ]) = make_float4(ct[8],  ct[9],  ct[10], ct[11]);
    *(float4*)(&ctp[w][o1 + 4]) = make_float4(ct[12], ct[13], ct[14], ct[15]);
    if (lane == 0) { mw[w] = m; sw[w] = s; }
    __syncthreads();

    float M = -1e30f;
    #pragma unroll
    for (int j = 0; j < NW; ++j) M = fmaxf(M, mw[j]);
    float denom = 0.f, sc[NW];
    #pragma unroll
    for (int j = 0; j < NW; ++j) { sc[j] = __expf(mw[j] - M); denom += sc[j] * sw[j]; }
    const float inv = 1.0f / denom;

    float acc = 0.f;
    #pragma unroll
    for (int j = 0; j < NW; ++j) acc += sc[j] * ctp[j][tid];
    out[b * DD + tid] = acc * inv;
}

// ---------------------------------------------------------------------------
extern "C" void kernel_launch(void* const* d_in, const int* in_sizes, int n_in,
                              void* d_out, int out_size, void* d_ws, size_t ws_size,
                              hipStream_t stream) {
    const int*   tokens = (const int*)d_in[0];
    // d_in[1] = max_len (scalar), fixed to LL
    const float* emb    = (const float*)d_in[2];
    const float* W      = (const float*)d_in[3];
    float*       out    = (float*)d_out;

    float*  hidden = (float*)d_ws;                       // 1 MB
    float*  q      = hidden + BB * DD;                   // 1 MB
    __half* embh   = (__half*)(q + BB * DD);             // ~98 MB

    const int nchunks = VROWS * (DD / 8);
    k_convert<<<(nchunks + 255) / 256, 256, 0, stream>>>(emb, embh);
    k_hidden<<<BB, 1024, 0, stream>>>(tokens, embh, hidden);
    dim3 g2(DD / 64, BB / 4);
    k_q<<<g2, 256, 0, stream>>>(hidden, W, q);
    k_attn<<<BB, 1024, 0, stream>>>(tokens, embh, q, out);
}